// Round 5
// baseline (214.502 us; speedup 1.0000x reference)
//
#include <hip/hip_runtime.h>
#include <hip/hip_fp16.h>

#define MF     16
#define PXB    512
#define WHALF_BYTES (1024 * 64 * 2)     // 128 KB fp16 per fern

__device__ __forceinline__ unsigned h2pack(float a, float b) {
    __half2 h = __floats2half2_rn(a, b);
    return __builtin_bit_cast(unsigned, h);
}

// D(f16x2) = W(f16x2) * broadcast(hi16(U) as f16) + D   — one instr, 2 MACs
#define PKFMA(D, W, U) \
    asm("v_pk_fma_f16 %0, %1, %2, %0 op_sel:[0,1,0] op_sel_hi:[1,1,1]" \
        : "+v"(D) : "v"(W), "v"(U))
// D(f16x2) = W(f16x2) * broadcast(hi16(U) as f16)
#define PKMUL(D, W, U) \
    asm("v_pk_mul_f16 %0, %1, %2 op_sel:[0,1] op_sel_hi:[1,1]" \
        : "=v"(D) : "v"(W), "v"(U))
// ACC(f32) += f16(lo/hi of P) * 1.0
#define MIXADD_LO(ACC, P) \
    asm("v_fma_mix_f32 %0, %1, 1.0, %0 op_sel:[0,0,0] op_sel_hi:[1,0,0]" \
        : "+v"(ACC) : "v"(P))
#define MIXADD_HI(ACC, P) \
    asm("v_fma_mix_f32 %0, %1, 1.0, %0 op_sel:[1,0,0] op_sel_hi:[1,0,0]" \
        : "+v"(ACC) : "v"(P))

// fp32 -> fp16 weight prepack (linear layout)
__global__ void prepack_kernel(const float* __restrict__ Wt, unsigned* __restrict__ wsH) {
    const int q = blockIdx.x * 256 + threadIdx.x;       // 524288 total
    const float2 f = ((const float2*)Wt)[q];
    wsH[q] = h2pack(f.x, f.y);
}

template<bool USE_WS>
__global__ __launch_bounds__(1024, 4)
void fern_kernel(const float* __restrict__ B, const float* __restrict__ Wt,
                 const unsigned* __restrict__ wsH,
                 const float* __restrict__ bias, float* __restrict__ out)
{
    // LDS (u32): [0,32768) weights fp16 linear; [32768,34816) param plane0
    // (p0..3); [34816,36864) param plane1 (p4..7). 144 KB total.
    // Epilogue reuses everything as float[64][513].
    __shared__ __align__(16) unsigned lds[36864];
    unsigned* ldsw = lds;
    unsigned* ldsp0 = lds + 32768;
    unsigned* ldsp1 = lds + 34816;

    const int t   = threadIdx.x;
    const int w   = t >> 6;
    const int ln  = t & 63;
    const int px8 = ln >> 3;
    const int cg  = ln & 7;
    const unsigned cg4 = (unsigned)cg << 4;   // byte offset within 128 B row

    const int gbase = blockIdx.x * PXB;
    const int n     = gbase >> 12;
    const int remb  = gbase & 4095;

    float acc[4][8];
#pragma unroll
    for (int r = 0; r < 4; ++r)
#pragma unroll
        for (int c = 0; c < 8; ++c) acc[r][c] = 0.f;

    const float* Bbase = B + (((size_t)n * (MF * 10)) << 12) + remb;

    // per-lane staging slots (uint4 units): fern-relative
    const int wslot = (w << 6) + ln;                    // 0..1023
    const uint4* wsU4 = (const uint4*)wsH;
    uint4* wdst = (uint4*)lds + wslot;

    // prologue: prefetch B bits for fern 0
    float T[10];
    if (t < 512) {
        const float* Bm = Bbase + t;
#pragma unroll
        for (int k = 0; k < 10; ++k) T[k] = Bm[(size_t)k << 12];
    }
    // prologue: prefetch weights for fern 0 into registers
    uint4 wreg[8];
    if (USE_WS) {
#pragma unroll
        for (int i = 0; i < 8; ++i) wreg[i] = wsU4[wslot + i * 1024];
    }

    for (int m = 0; m < MF; ++m) {
        // ---------- stage weights[m]: regs -> LDS (T14 write-late) ----------
        if (USE_WS) {
#pragma unroll
            for (int i = 0; i < 8; ++i) wdst[i * 1024] = wreg[i];
        } else {
            const float4* src4 = (const float4*)(Wt + ((size_t)m << 16));
#pragma unroll
            for (int i = 0; i < 8; ++i) {
                const int j = i * 1024 + t;
                const float4 f0 = src4[2 * j];
                const float4 f1 = src4[2 * j + 1];
                uint4 o;
                o.x = h2pack(f0.x, f0.y);
                o.y = h2pack(f0.z, f0.w);
                o.z = h2pack(f1.x, f1.y);
                o.w = h2pack(f1.z, f1.w);
                *(uint4*)&ldsw[j * 4] = o;
            }
        }

        // ---------- phase 1: per-pixel fern params ----------
        if (t < 512) {
            float BA[10]; float bsp = 1.f; int wb = 0;
#pragma unroll
            for (int k = 0; k < 10; ++k) {
                wb |= (T[k] >= 0.5f) ? (1 << k) : 0;
                bsp *= fmaxf(T[k], 1.f - T[k]);
                BA[k] = fabsf(T[k] - 0.5f);
            }
            int abi0, abi1, abi2; float aba0, aba1, aba2;
            {
                int bi = 0; float bv = BA[0]; float tv = T[0];
#pragma unroll
                for (int k = 1; k < 10; ++k) if (BA[k] < bv) { bv = BA[k]; bi = k; tv = T[k]; }
                abi0 = bi; aba0 = tv;
#pragma unroll
                for (int k = 0; k < 10; ++k) BA[k] = (k == bi) ? (BA[k] + 1.f) : BA[k];
            }
            {
                int bi = 0; float bv = BA[0]; float tv = T[0];
#pragma unroll
                for (int k = 1; k < 10; ++k) if (BA[k] < bv) { bv = BA[k]; bi = k; tv = T[k]; }
                abi1 = bi; aba1 = tv;
#pragma unroll
                for (int k = 0; k < 10; ++k) BA[k] = (k == bi) ? (BA[k] + 1.f) : BA[k];
            }
            {
                int bi = 0; float bv = BA[0]; float tv = T[0];
#pragma unroll
                for (int k = 1; k < 10; ++k) if (BA[k] < bv) { bv = BA[k]; bi = k; tv = T[k]; }
                abi2 = bi; aba2 = tv;
            }
            const float m0 = fmaxf(aba0, 1.f - aba0);
            const float m1 = fmaxf(aba1, 1.f - aba1);
            const float m2 = fmaxf(aba2, 1.f - aba2);
            const float bspA = bsp * __builtin_amdgcn_rcpf(m0 * m1 * m2);
            const int mk0 = 1 << abi0, mk1 = 1 << abi1, mk2 = 1 << abi2;
            unsigned uu[8];
#pragma unroll
            for (int p = 0; p < 8; ++p) {
                float at = ((p & 1) ? aba0 : (1.f - aba0));
                at      *= ((p & 2) ? aba1 : (1.f - aba1));
                at      *= ((p & 4) ? aba2 : (1.f - aba2));
                at      *= bspA;
                int it = wb;
                it = (p & 1) ? (it | mk0) : (it & ~mk0);
                it = (p & 2) ? (it | mk1) : (it & ~mk1);
                it = (p & 4) ? (it | mk2) : (it & ~mk2);
                uu[p] = ((unsigned)__half_as_ushort(__float2half_rn(at)) << 16)
                      | ((unsigned)it << 4);
            }
            *(uint4*)&ldsp0[t * 4] = make_uint4(uu[0], uu[1], uu[2], uu[3]);
            *(uint4*)&ldsp1[t * 4] = make_uint4(uu[4], uu[5], uu[6], uu[7]);
        }

        // prefetch next fern's B bits (consumed by next iteration's phase 1)
        if (t < 512 && m + 1 < MF) {
            const float* Bm = Bbase + (((size_t)(m + 1) * 10) << 12) + t;
#pragma unroll
            for (int k = 0; k < 10; ++k) T[k] = Bm[(size_t)k << 12];
        }
        __syncthreads();   // weights + params visible

        // issue weight prefetch for m+1 (in flight across phase 2)
        if (USE_WS && m + 1 < MF) {
            const size_t fb = (size_t)(m + 1) * 8192 + (size_t)wslot;
#pragma unroll
            for (int i = 0; i < 8; ++i) wreg[i] = wsU4[fb + i * 1024];
        }

        // ---------- phase 2: gather + packed-fp16 accumulate ----------
#pragma unroll
        for (int r = 0; r < 4; ++r) {
            const int pxl = w * 32 + r * 8 + px8;
            const uint4 pa = *(const uint4*)&ldsp0[pxl * 4];
            const uint4 pb = *(const uint4*)&ldsp1[pxl * 4];
            const unsigned pu[8] = {pa.x, pa.y, pa.z, pa.w, pb.x, pb.y, pb.z, pb.w};
            unsigned a01, a23, a45, a67;     // fp16-pair per-fern partials
            {
                const unsigned u = pu[0];
                const unsigned boff = ((u & 0x3FF0u) << 3) + cg4;
                const uint4 w4 = *(const uint4*)((const char*)ldsw + boff);
                PKMUL(a01, w4.x, u);
                PKMUL(a23, w4.y, u);
                PKMUL(a45, w4.z, u);
                PKMUL(a67, w4.w, u);
            }
#pragma unroll
            for (int p = 1; p < 8; ++p) {
                const unsigned u = pu[p];
                const unsigned boff = ((u & 0x3FF0u) << 3) + cg4;
                const uint4 w4 = *(const uint4*)((const char*)ldsw + boff);
                PKFMA(a01, w4.x, u);
                PKFMA(a23, w4.y, u);
                PKFMA(a45, w4.z, u);
                PKFMA(a67, w4.w, u);
            }
            MIXADD_LO(acc[r][0], a01); MIXADD_HI(acc[r][1], a01);
            MIXADD_LO(acc[r][2], a23); MIXADD_HI(acc[r][3], a23);
            MIXADD_LO(acc[r][4], a45); MIXADD_HI(acc[r][5], a45);
            MIXADD_LO(acc[r][6], a67); MIXADD_HI(acc[r][7], a67);
        }
        __syncthreads();   // phase-2 reads done before next stage/params overwrite
    }

    // ---------- epilogue: LDS transpose (stride 513), bias, coalesced store ----------
    float* ldst = (float*)lds;
#pragma unroll
    for (int r = 0; r < 4; ++r) {
        const int pxl = w * 32 + r * 8 + px8;
#pragma unroll
        for (int c = 0; c < 8; ++c)
            ldst[(cg * 8 + c) * 513 + pxl] = acc[r][c];
    }
    __syncthreads();
    const int tt = t & 511, hh = t >> 9;
    const size_t obase = ((size_t)n << 18) + (size_t)(remb + tt);
#pragma unroll
    for (int d = 0; d < 32; ++d) {
        const int ch = hh * 32 + d;
        out[obase + ((size_t)ch << 12)] = ldst[ch * 513 + tt] + bias[ch];
    }
}

extern "C" void kernel_launch(void* const* d_in, const int* in_sizes, int n_in,
                              void* d_out, int out_size, void* d_ws, size_t ws_size,
                              hipStream_t stream) {
    (void)in_sizes; (void)n_in; (void)out_size;
    const float* B    = (const float*)d_in[0];
    const float* Wt   = (const float*)d_in[1];
    const float* bias = (const float*)d_in[2];
    float* out        = (float*)d_out;

    const size_t need = (size_t)MF * WHALF_BYTES;   // 2 MB fp16 weights
    if (ws_size >= need) {
        unsigned* wsH = (unsigned*)d_ws;
        hipLaunchKernelGGL(prepack_kernel, dim3(2048), dim3(256), 0, stream, Wt, wsH);
        hipLaunchKernelGGL((fern_kernel<true>), dim3(256), dim3(1024), 0, stream,
                           B, Wt, wsH, bias, out);
    } else {
        hipLaunchKernelGGL((fern_kernel<false>), dim3(256), dim3(1024), 0, stream,
                           B, Wt, (const unsigned*)nullptr, bias, out);
    }
}

// Round 6
// 86.815 us; speedup vs baseline: 2.4708x; 2.4708x over previous
//
#include <hip/hip_runtime.h>
#include <hip/hip_fp16.h>

#define MF     16
#define PXB    512
#define WHALF_BYTES (1024 * 64 * 2)     // 128 KB fp16 per fern

typedef const __attribute__((address_space(1))) unsigned gu32_t;
typedef __attribute__((address_space(3))) unsigned lu32_t;

__device__ __forceinline__ void gl_lds16(const void* g, void* l) {
    __builtin_amdgcn_global_load_lds((gu32_t*)g, (lu32_t*)l, 16, 0, 0);
}

__device__ __forceinline__ unsigned h2pack(float a, float b) {
    __half2 h = __floats2half2_rn(a, b);
    return __builtin_bit_cast(unsigned, h);
}

// D(f16x2) = W(f16x2) * broadcast(hi16(U) as f16) + D   — one instr, 2 MACs
#define PKFMA(D, W, U) \
    asm("v_pk_fma_f16 %0, %1, %2, %0 op_sel:[0,1,0] op_sel_hi:[1,1,1]" \
        : "+v"(D) : "v"(W), "v"(U))
// D(f16x2) = W(f16x2) * broadcast(hi16(U) as f16)
#define PKMUL(D, W, U) \
    asm("v_pk_mul_f16 %0, %1, %2 op_sel:[0,1] op_sel_hi:[1,1]" \
        : "=v"(D) : "v"(W), "v"(U))
// ACC(f32) += f16(lo/hi of P) * 1.0
#define MIXADD_LO(ACC, P) \
    asm("v_fma_mix_f32 %0, %1, 1.0, %0 op_sel:[0,0,0] op_sel_hi:[1,0,0]" \
        : "+v"(ACC) : "v"(P))
#define MIXADD_HI(ACC, P) \
    asm("v_fma_mix_f32 %0, %1, 1.0, %0 op_sel:[1,0,0] op_sel_hi:[1,0,0]" \
        : "+v"(ACC) : "v"(P))

// fp32 -> fp16 weight prepack (linear layout)
__global__ void prepack_kernel(const float* __restrict__ Wt, unsigned* __restrict__ wsH) {
    const int q = blockIdx.x * 256 + threadIdx.x;       // 524288 total
    const float2 f = ((const float2*)Wt)[q];
    wsH[q] = h2pack(f.x, f.y);
}

template<bool USE_WS>
__global__ __launch_bounds__(1024, 4)
void fern_kernel(const float* __restrict__ B, const float* __restrict__ Wt,
                 const unsigned* __restrict__ wsH,
                 const float* __restrict__ bias, float* __restrict__ out)
{
    // LDS (u32): [0,32768) weights fp16 linear; [32768,34816) param plane0
    // (p0..3); [34816,36864) param plane1 (p4..7). 144 KB total.
    // Epilogue reuses everything as float[64][513].
    __shared__ __align__(16) unsigned lds[36864];
    unsigned* ldsw = lds;
    unsigned* ldsp0 = lds + 32768;
    unsigned* ldsp1 = lds + 34816;

    const int t   = threadIdx.x;
    const int w   = t >> 6;
    const int ln  = t & 63;
    const int px8 = ln >> 3;
    const int cg  = ln & 7;
    const unsigned cg4 = (unsigned)cg << 4;   // byte offset within 128 B row

    const int gbase = blockIdx.x * PXB;
    const int n     = gbase >> 12;
    const int remb  = gbase & 4095;

    float acc[4][8];
#pragma unroll
    for (int r = 0; r < 4; ++r)
#pragma unroll
        for (int c = 0; c < 8; ++c) acc[r][c] = 0.f;

    const float* Bbase = B + (((size_t)n * (MF * 10)) << 12) + remb;

    // prologue: prefetch B bits for fern 0
    float T[10];
    if (t < 512) {
        const float* Bm = Bbase + t;
#pragma unroll
        for (int k = 0; k < 10; ++k) T[k] = Bm[(size_t)k << 12];
    }

    for (int m = 0; m < MF; ++m) {
        // ---------- stage weights[m] -> LDS (async DMA) ----------
        if (USE_WS) {
            const char* g = (const char*)wsH + (size_t)m * WHALF_BYTES + (w << 10) + (ln << 4);
            char* l = (char*)lds + (w << 10);
#pragma unroll
            for (int i = 0; i < 8; ++i)
                gl_lds16(g + i * 16384, l + i * 16384);
        } else {
            const float4* src4 = (const float4*)(Wt + ((size_t)m << 16));
#pragma unroll
            for (int i = 0; i < 8; ++i) {
                const int j = i * 1024 + t;
                const float4 f0 = src4[2 * j];
                const float4 f1 = src4[2 * j + 1];
                uint4 o;
                o.x = h2pack(f0.x, f0.y);
                o.y = h2pack(f0.z, f0.w);
                o.z = h2pack(f1.x, f1.y);
                o.w = h2pack(f1.z, f1.w);
                *(uint4*)&ldsw[j * 4] = o;
            }
        }

        // ---------- phase 1: per-pixel fern params ----------
        if (t < 512) {
            float BA[10]; float bsp = 1.f; int wb = 0;
#pragma unroll
            for (int k = 0; k < 10; ++k) {
                wb |= (T[k] >= 0.5f) ? (1 << k) : 0;
                bsp *= fmaxf(T[k], 1.f - T[k]);
                BA[k] = fabsf(T[k] - 0.5f);
            }
            int abi0, abi1, abi2; float aba0, aba1, aba2;
            {
                int bi = 0; float bv = BA[0]; float tv = T[0];
#pragma unroll
                for (int k = 1; k < 10; ++k) if (BA[k] < bv) { bv = BA[k]; bi = k; tv = T[k]; }
                abi0 = bi; aba0 = tv;
#pragma unroll
                for (int k = 0; k < 10; ++k) BA[k] = (k == bi) ? (BA[k] + 1.f) : BA[k];
            }
            {
                int bi = 0; float bv = BA[0]; float tv = T[0];
#pragma unroll
                for (int k = 1; k < 10; ++k) if (BA[k] < bv) { bv = BA[k]; bi = k; tv = T[k]; }
                abi1 = bi; aba1 = tv;
#pragma unroll
                for (int k = 0; k < 10; ++k) BA[k] = (k == bi) ? (BA[k] + 1.f) : BA[k];
            }
            {
                int bi = 0; float bv = BA[0]; float tv = T[0];
#pragma unroll
                for (int k = 1; k < 10; ++k) if (BA[k] < bv) { bv = BA[k]; bi = k; tv = T[k]; }
                abi2 = bi; aba2 = tv;
            }
            const float m0 = fmaxf(aba0, 1.f - aba0);
            const float m1 = fmaxf(aba1, 1.f - aba1);
            const float m2 = fmaxf(aba2, 1.f - aba2);
            const float bspA = bsp * __builtin_amdgcn_rcpf(m0 * m1 * m2);
            const int mk0 = 1 << abi0, mk1 = 1 << abi1, mk2 = 1 << abi2;
            unsigned uu[8];
#pragma unroll
            for (int p = 0; p < 8; ++p) {
                float at = ((p & 1) ? aba0 : (1.f - aba0));
                at      *= ((p & 2) ? aba1 : (1.f - aba1));
                at      *= ((p & 4) ? aba2 : (1.f - aba2));
                at      *= bspA;
                int it = wb;
                it = (p & 1) ? (it | mk0) : (it & ~mk0);
                it = (p & 2) ? (it | mk1) : (it & ~mk1);
                it = (p & 4) ? (it | mk2) : (it & ~mk2);
                uu[p] = ((unsigned)__half_as_ushort(__float2half_rn(at)) << 16)
                      | ((unsigned)it << 4);
            }
            *(uint4*)&ldsp0[t * 4] = make_uint4(uu[0], uu[1], uu[2], uu[3]);
            *(uint4*)&ldsp1[t * 4] = make_uint4(uu[4], uu[5], uu[6], uu[7]);
        }

        // prefetch next fern's B bits (consumed by next iteration's phase 1)
        if (t < 512 && m + 1 < MF) {
            const float* Bm = Bbase + (((size_t)(m + 1) * 10) << 12) + t;
#pragma unroll
            for (int k = 0; k < 10; ++k) T[k] = Bm[(size_t)k << 12];
        }
        __syncthreads();   // staging drained + params visible

        // ---------- phase 2: gather + packed-fp16 accumulate ----------
        // p 0..4 gather from LDS; p 5..7 gather from L2 (weights are L2-resident)
        const char* wg = (const char*)wsH + (size_t)m * WHALF_BYTES;
#pragma unroll
        for (int r = 0; r < 4; ++r) {
            const int pxl = w * 32 + r * 8 + px8;
            const uint4 pa = *(const uint4*)&ldsp0[pxl * 4];
            const uint4 pb = *(const uint4*)&ldsp1[pxl * 4];
            const unsigned pu[8] = {pa.x, pa.y, pa.z, pa.w, pb.x, pb.y, pb.z, pb.w};

            uint4 g5, g6, g7;
            if (USE_WS) {   // issue L2 gathers first; latency hides under LDS work
                g5 = *(const uint4*)(wg + (((pu[5] & 0x3FF0u) << 3) + cg4));
                g6 = *(const uint4*)(wg + (((pu[6] & 0x3FF0u) << 3) + cg4));
                g7 = *(const uint4*)(wg + (((pu[7] & 0x3FF0u) << 3) + cg4));
            }

            unsigned a01, a23, a45, a67;     // fp16-pair per-fern partials
            {
                const unsigned u = pu[0];
                const unsigned boff = ((u & 0x3FF0u) << 3) + cg4;
                const uint4 w4 = *(const uint4*)((const char*)ldsw + boff);
                PKMUL(a01, w4.x, u);
                PKMUL(a23, w4.y, u);
                PKMUL(a45, w4.z, u);
                PKMUL(a67, w4.w, u);
            }
#pragma unroll
            for (int p = 1; p < 5; ++p) {
                const unsigned u = pu[p];
                const unsigned boff = ((u & 0x3FF0u) << 3) + cg4;
                const uint4 w4 = *(const uint4*)((const char*)ldsw + boff);
                PKFMA(a01, w4.x, u);
                PKFMA(a23, w4.y, u);
                PKFMA(a45, w4.z, u);
                PKFMA(a67, w4.w, u);
            }
            if (USE_WS) {
                PKFMA(a01, g5.x, pu[5]); PKFMA(a23, g5.y, pu[5]);
                PKFMA(a45, g5.z, pu[5]); PKFMA(a67, g5.w, pu[5]);
                PKFMA(a01, g6.x, pu[6]); PKFMA(a23, g6.y, pu[6]);
                PKFMA(a45, g6.z, pu[6]); PKFMA(a67, g6.w, pu[6]);
                PKFMA(a01, g7.x, pu[7]); PKFMA(a23, g7.y, pu[7]);
                PKFMA(a45, g7.z, pu[7]); PKFMA(a67, g7.w, pu[7]);
            } else {
#pragma unroll
                for (int p = 5; p < 8; ++p) {
                    const unsigned u = pu[p];
                    const unsigned boff = ((u & 0x3FF0u) << 3) + cg4;
                    const uint4 w4 = *(const uint4*)((const char*)ldsw + boff);
                    PKFMA(a01, w4.x, u);
                    PKFMA(a23, w4.y, u);
                    PKFMA(a45, w4.z, u);
                    PKFMA(a67, w4.w, u);
                }
            }
            MIXADD_LO(acc[r][0], a01); MIXADD_HI(acc[r][1], a01);
            MIXADD_LO(acc[r][2], a23); MIXADD_HI(acc[r][3], a23);
            MIXADD_LO(acc[r][4], a45); MIXADD_HI(acc[r][5], a45);
            MIXADD_LO(acc[r][6], a67); MIXADD_HI(acc[r][7], a67);
        }
        __syncthreads();   // phase-2 reads done before next stage/params overwrite
    }

    // ---------- epilogue: LDS transpose (stride 513), bias, coalesced store ----------
    float* ldst = (float*)lds;
#pragma unroll
    for (int r = 0; r < 4; ++r) {
        const int pxl = w * 32 + r * 8 + px8;
#pragma unroll
        for (int c = 0; c < 8; ++c)
            ldst[(cg * 8 + c) * 513 + pxl] = acc[r][c];
    }
    __syncthreads();
    const int tt = t & 511, hh = t >> 9;
    const size_t obase = ((size_t)n << 18) + (size_t)(remb + tt);
#pragma unroll
    for (int d = 0; d < 32; ++d) {
        const int ch = hh * 32 + d;
        out[obase + ((size_t)ch << 12)] = ldst[ch * 513 + tt] + bias[ch];
    }
}

extern "C" void kernel_launch(void* const* d_in, const int* in_sizes, int n_in,
                              void* d_out, int out_size, void* d_ws, size_t ws_size,
                              hipStream_t stream) {
    (void)in_sizes; (void)n_in; (void)out_size;
    const float* B    = (const float*)d_in[0];
    const float* Wt   = (const float*)d_in[1];
    const float* bias = (const float*)d_in[2];
    float* out        = (float*)d_out;

    const size_t need = (size_t)MF * WHALF_BYTES;   // 2 MB fp16 weights
    if (ws_size >= need) {
        unsigned* wsH = (unsigned*)d_ws;
        hipLaunchKernelGGL(prepack_kernel, dim3(2048), dim3(256), 0, stream, Wt, wsH);
        hipLaunchKernelGGL((fern_kernel<true>), dim3(256), dim3(1024), 0, stream,
                           B, Wt, wsH, bias, out);
    } else {
        hipLaunchKernelGGL((fern_kernel<false>), dim3(256), dim3(1024), 0, stream,
                           B, Wt, (const unsigned*)nullptr, bias, out);
    }
}